// Round 1
// baseline (38564.191 us; speedup 1.0000x reference)
//
#include <hip/hip_runtime.h>
#include <hip/hip_bf16.h>

#define T_LEN 2048
#define DIN 128
#define NH 256
#define DOUT 128
#define G4H 1024

typedef float f32x4 __attribute__((ext_vector_type(4)));
typedef float f32x2 __attribute__((ext_vector_type(2)));
typedef __bf16 bf16x8 __attribute__((ext_vector_type(8)));

__device__ __forceinline__ __bf16 f2bf(float f) {
    union { float f; unsigned u; } v; v.f = f;
    unsigned r = v.u + 0x7fffu + ((v.u >> 16) & 1u);   // RNE
    union { unsigned short u; __bf16 b; } o; o.u = (unsigned short)(r >> 16);
    return o.b;
}

__device__ __forceinline__ float sigf(float x) {
    return 1.0f / (1.0f + __expf(-x));
}
__device__ __forceinline__ float tanh_(float x) {
    float ax = fabsf(x);
    float e = __expf(-2.0f * ax);
    float r = (1.0f - e) / (1.0f + e);
    return x < 0.0f ? -r : r;
}

// One block = 16 batches, full hidden state. 16 waves; wave w owns permuted
// gate-columns q in [64w, 64w+64): q = 64w + 16g + u  <->  orig col = 256g + 16w + u.
// Lane l: u = l&15 (unit j = 16w+u, also MFMA col), k-group = l>>4.
// C layout (m89): col = l&15, row = 4*(l>>4)+reg  -> each lane holds 4 batches x
// {i,f,g,o} of ONE unit -> lane-local cell update.
__global__ __launch_bounds__(1024) void lstm_fused(
    const float* __restrict__ x,   const float* __restrict__ Wx,
    const float* __restrict__ Wh,  const float* __restrict__ bias,
    const float* __restrict__ fcw, const float* __restrict__ fcb,
    float* __restrict__ out)
{
    const int bg  = blockIdx.x;      // batch group: batches [16bg, 16bg+16)
    const int tid = threadIdx.x;
    const int w   = tid >> 6;        // wave 0..15
    const int l   = tid & 63;
    const int lu  = l & 15;
    const int lk  = l >> 4;

    __shared__ __align__(16) __bf16 h_lds[2][16 * 256];  // swizzled rows
    __shared__ __align__(16) __bf16 x_lds[2][16 * 128];  // swizzled rows
    __shared__ float hf[16 * 256];

    // ---- register-resident weights (B-fragments, permuted columns) ----
    bf16x8 wh[8][4];
    #pragma unroll
    for (int kt = 0; kt < 8; ++kt) {
        #pragma unroll
        for (int g = 0; g < 4; ++g) {
            bf16x8 f;
            #pragma unroll
            for (int e = 0; e < 8; ++e) {
                int k   = kt * 32 + lk * 8 + e;
                int col = g * 256 + w * 16 + lu;
                f[e] = f2bf(Wh[k * G4H + col]);
            }
            wh[kt][g] = f;
        }
    }
    bf16x8 wx[4][4];
    #pragma unroll
    for (int kt = 0; kt < 4; ++kt) {
        #pragma unroll
        for (int g = 0; g < 4; ++g) {
            bf16x8 f;
            #pragma unroll
            for (int e = 0; e < 8; ++e) {
                int k   = kt * 32 + lk * 8 + e;
                int col = g * 256 + w * 16 + lu;
                f[e] = f2bf(Wx[k * G4H + col]);
            }
            wx[kt][g] = f;
        }
    }
    float bv[4];
    #pragma unroll
    for (int g = 0; g < 4; ++g) bv[g] = bias[g * 256 + w * 16 + lu];

    // ---- init: h=0, stage x[t=0] ----
    for (int i = tid; i < 16 * 256; i += 1024) h_lds[0][i] = f2bf(0.0f);
    {
        const float* xr = x + ((size_t)(bg * 16 + w) * T_LEN + 0) * DIN;
        f32x2 v = *(const f32x2*)(xr + 2 * l);
        int idx = (w * 128 + 2 * l) ^ ((w & 7) << 3);
        x_lds[0][idx]     = f2bf(v.x);
        x_lds[0][idx + 1] = f2bf(v.y);
    }

    float cc[4]   = {0.f, 0.f, 0.f, 0.f};
    float hreg[4] = {0.f, 0.f, 0.f, 0.f};
    int cur = 0;
    __syncthreads();

    for (int t = 0; t < T_LEN; ++t) {
        // prefetch x[t+1] (no dependency; hidden under MFMAs)
        int tn = (t + 1 < T_LEN) ? (t + 1) : t;
        f32x2 xpre = *(const f32x2*)(x + ((size_t)(bg * 16 + w) * T_LEN + tn) * DIN + 2 * l);

        f32x4 acc[4];
        #pragma unroll
        for (int g = 0; g < 4; ++g) {
            #pragma unroll
            for (int r = 0; r < 4; ++r) acc[g][r] = bv[g];
        }

        // x_t @ Wx  (K = 128)
        #pragma unroll
        for (int kt = 0; kt < 4; ++kt) {
            bf16x8 a = *(const bf16x8*)&x_lds[cur][(lu * 128 + kt * 32 + lk * 8) ^ ((lu & 7) << 3)];
            #pragma unroll
            for (int g = 0; g < 4; ++g)
                acc[g] = __builtin_amdgcn_mfma_f32_16x16x32_bf16(a, wx[kt][g], acc[g], 0, 0, 0);
        }
        // h_t @ Wh  (K = 256)
        #pragma unroll
        for (int kt = 0; kt < 8; ++kt) {
            bf16x8 a = *(const bf16x8*)&h_lds[cur][(lu * 256 + kt * 32 + lk * 8) ^ ((lu & 7) << 3)];
            #pragma unroll
            for (int g = 0; g < 4; ++g)
                acc[g] = __builtin_amdgcn_mfma_f32_16x16x32_bf16(a, wh[kt][g], acc[g], 0, 0, 0);
        }

        // gates + cell update (lane-local), write h_{t+1} (bf16) to other buffer
        #pragma unroll
        for (int r = 0; r < 4; ++r) {
            float iv = sigf(acc[0][r]);
            float fv = sigf(acc[1][r]);
            float gv = tanh_(acc[2][r]);
            float ov = sigf(acc[3][r]);
            cc[r]   = fv * cc[r] + iv * gv;
            hreg[r] = ov * tanh_(cc[r]);
            int m = lk * 4 + r;
            h_lds[cur ^ 1][(m * 256 + w * 16 + lu) ^ ((m & 7) << 3)] = f2bf(hreg[r]);
        }
        // stage prefetched x[t+1]
        {
            int idx = (w * 128 + 2 * l) ^ ((w & 7) << 3);
            x_lds[cur ^ 1][idx]     = f2bf(xpre.x);
            x_lds[cur ^ 1][idx + 1] = f2bf(xpre.y);
        }
        cur ^= 1;
        __syncthreads();
    }

    // ---- final FC: out[16bg+m][d] = h[m] . fcw[:,d] + fcb[d] (f32) ----
    #pragma unroll
    for (int r = 0; r < 4; ++r) {
        int m = lk * 4 + r;
        hf[m * 256 + w * 16 + lu] = hreg[r];
    }
    __syncthreads();
    for (int d = l; d < DOUT; d += 64) {
        float s = fcb[d];
        for (int j = 0; j < NH; ++j) s += hf[w * 256 + j] * fcw[j * DOUT + d];
        out[(bg * 16 + w) * DOUT + d] = s;
    }
}

extern "C" void kernel_launch(void* const* d_in, const int* in_sizes, int n_in,
                              void* d_out, int out_size, void* d_ws, size_t ws_size,
                              hipStream_t stream) {
    (void)in_sizes; (void)n_in; (void)d_ws; (void)ws_size; (void)out_size;
    const float* x   = (const float*)d_in[0];
    const float* Wx  = (const float*)d_in[1];
    const float* Wh  = (const float*)d_in[2];
    const float* b   = (const float*)d_in[3];
    const float* fcw = (const float*)d_in[4];
    const float* fcb = (const float*)d_in[5];
    float* out = (float*)d_out;

    hipLaunchKernelGGL(lstm_fused, dim3(4), dim3(1024), 0, stream,
                       x, Wx, Wh, b, fcw, fcb, out);
}

// Round 3
// 12209.237 us; speedup vs baseline: 3.1586x; 3.1586x over previous
//
#include <hip/hip_runtime.h>
#include <hip/hip_bf16.h>

#define T_LEN 2048
#define DIN   128
#define NH    256
#define G4H   1024
#define DOUT  128

typedef float  f32x4  __attribute__((ext_vector_type(4)));
typedef __bf16 bf16x8 __attribute__((ext_vector_type(8)));

__device__ __forceinline__ __bf16 f2bf(float f) {
    union { float f; unsigned u; } v; v.f = f;
    unsigned r = v.u + 0x7fffu + ((v.u >> 16) & 1u);   // RNE
    union { unsigned short u; __bf16 b; } o; o.u = (unsigned short)(r >> 16);
    return o.b;
}
__device__ __forceinline__ float sigf(float x) { return 1.0f / (1.0f + __expf(-x)); }
__device__ __forceinline__ float tanh_(float x) {
    float ax = fabsf(x);
    float e  = __expf(-2.0f * ax);
    float r  = (1.0f - e) / (1.0f + e);
    return x < 0.0f ? -r : r;
}

// ws layout (FIXED in round 3 — round 2 under-sized hbuf by 2x and overlapped hfinal):
//   [0,     1024)   : unsigned cnt[4], one per batch group, 256B stride
//   [1024,  66560)  : __bf16 hbuf[2][4][16][256]   ping-pong hidden state (65536 B)
//   [66560, 132096) : float  hfinal[4][16][256]    f32 h_T for the FC      (65536 B)
//
// Grid: 32 blocks x 256 thr. Block id: bg = id&7 (>=4 -> idle), cb = id>>3.
// Wave w owns units [cb*64 + w*16, +16) x 4 gates.
// MFMA 16x16x32 maps (verified round 1): A row = l&15 (batch), A k = (l>>4)*8+e;
// B col = l&15 (unit), B k = (l>>4)*8+e; C col = l&15, row = 4*(l>>4)+reg.
__global__ __launch_bounds__(256, 1) void lstm_scan(
    const float* __restrict__ x,   const float* __restrict__ Wx,
    const float* __restrict__ Wh,  const float* __restrict__ bias,
    const float* __restrict__ fcw, const float* __restrict__ fcb,
    float* __restrict__ out, void* __restrict__ ws)
{
    const int id  = blockIdx.x;
    const int xcd = id & 7;
    if (xcd >= 4) return;               // 16 idle blocks (XCD co-location swizzle)
    const int bg  = xcd;                // batch group: batches [16bg, 16bg+16)
    const int cb  = id >> 3;            // column block 0..3
    const int tid = threadIdx.x;
    const int w   = tid >> 6;
    const int l   = tid & 63;
    const int lu  = l & 15;
    const int lk  = l >> 4;
    const int ub  = cb * 64 + w * 16;   // first hidden unit owned by this wave

    unsigned* cnt  = (unsigned*)ws + bg * 64;
    __bf16*   hb   = (__bf16*)((char*)ws + 1024);
    float*    hfin = (float*)((char*)ws + 66560);

    // ---- register-resident weights (bf16 B-fragments, wave's 64 gate-cols) ----
    bf16x8 whf[8][4];
    #pragma unroll
    for (int kt = 0; kt < 8; ++kt)
        #pragma unroll
        for (int g = 0; g < 4; ++g) {
            bf16x8 f;
            #pragma unroll
            for (int e = 0; e < 8; ++e)
                f[e] = f2bf(Wh[(kt*32 + lk*8 + e) * G4H + g*256 + ub + lu]);
            whf[kt][g] = f;
        }
    bf16x8 wxf[4][4];
    #pragma unroll
    for (int kt = 0; kt < 4; ++kt)
        #pragma unroll
        for (int g = 0; g < 4; ++g) {
            bf16x8 f;
            #pragma unroll
            for (int e = 0; e < 8; ++e)
                f[e] = f2bf(Wx[(kt*32 + lk*8 + e) * G4H + g*256 + ub + lu]);
            wxf[kt][g] = f;
        }
    float bv[4];
    #pragma unroll
    for (int g = 0; g < 4; ++g) bv[g] = bias[g*256 + ub + lu];

    // ---- prefetch x[t=0] A-fragments (f32, converted at loop top) ----
    const float* xrow = x + (size_t)(bg*16 + lu) * (size_t)(T_LEN * DIN);
    f32x4 xp[4][2];
    #pragma unroll
    for (int kt = 0; kt < 4; ++kt) {
        const float* p = xrow + kt*32 + lk*8;
        xp[kt][0] = *(const f32x4*)p;
        xp[kt][1] = *(const f32x4*)(p + 4);
    }

    float cc[4] = {0.f, 0.f, 0.f, 0.f};
    float hv[4] = {0.f, 0.f, 0.f, 0.f};

    for (int t = 0; t < T_LEN; ++t) {
        // convert prefetched x_t, then issue prefetch of x_{t+1}
        bf16x8 xa[4];
        #pragma unroll
        for (int kt = 0; kt < 4; ++kt) {
            #pragma unroll
            for (int e = 0; e < 4; ++e) {
                xa[kt][e]     = f2bf(xp[kt][0][e]);
                xa[kt][e + 4] = f2bf(xp[kt][1][e]);
            }
        }
        {
            int tn = (t + 1 < T_LEN) ? t + 1 : t;
            const float* p = xrow + (size_t)tn * DIN + lk*8;
            #pragma unroll
            for (int kt = 0; kt < 4; ++kt) {
                xp[kt][0] = *(const f32x4*)(p + kt*32);
                xp[kt][1] = *(const f32x4*)(p + kt*32 + 4);
            }
        }

        f32x4 acc[4];
        #pragma unroll
        for (int g = 0; g < 4; ++g) { f32x4 a = {bv[g], bv[g], bv[g], bv[g]}; acc[g] = a; }

        // x part first: independent of h, hides the sync
        #pragma unroll
        for (int kt = 0; kt < 4; ++kt)
            #pragma unroll
            for (int g = 0; g < 4; ++g)
                acc[g] = __builtin_amdgcn_mfma_f32_16x16x32_bf16(xa[kt], wxf[kt][g], acc[g], 0, 0, 0);

        // wait until all 16 waves of this bg published h_t
        {
            unsigned tgt = 16u * (unsigned)t;
            while (__hip_atomic_load(cnt, __ATOMIC_RELAXED, __HIP_MEMORY_SCOPE_AGENT) < tgt) {}
            __builtin_amdgcn_fence(__ATOMIC_ACQUIRE, "agent");
        }

        // h part
        const __bf16* hrow = hb + (((size_t)(t & 1) * 4 + bg) * 16 + lu) * 256;
        #pragma unroll
        for (int kt = 0; kt < 8; ++kt) {
            bf16x8 ha = *(const bf16x8*)(hrow + kt*32 + lk*8);
            #pragma unroll
            for (int g = 0; g < 4; ++g)
                acc[g] = __builtin_amdgcn_mfma_f32_16x16x32_bf16(ha, whf[kt][g], acc[g], 0, 0, 0);
        }

        // gates + cell update (lane-local), publish h_{t+1}
        __bf16* hwp = hb + (((size_t)((t + 1) & 1) * 4 + bg) * 16) * 256 + ub + lu;
        #pragma unroll
        for (int r = 0; r < 4; ++r) {
            float iv = sigf(acc[0][r]);
            float fv = sigf(acc[1][r]);
            float gv = tanh_(acc[2][r]);
            float ov = sigf(acc[3][r]);
            cc[r] = fv * cc[r] + iv * gv;
            hv[r] = ov * tanh_(cc[r]);
            hwp[(lk*4 + r) * 256] = f2bf(hv[r]);
        }
        if (t == T_LEN - 1) {
            #pragma unroll
            for (int r = 0; r < 4; ++r)
                hfin[((size_t)bg * 16 + lk*4 + r) * 256 + ub + lu] = hv[r];
        }
        __builtin_amdgcn_fence(__ATOMIC_RELEASE, "agent");
        if (l == 0) __hip_atomic_fetch_add(cnt, 1u, __ATOMIC_RELAXED, __HIP_MEMORY_SCOPE_AGENT);
    }

    // ---- final FC: block (bg,cb) -> out rows [16bg,+16), cols [32cb,+32) ----
    while (__hip_atomic_load(cnt, __ATOMIC_RELAXED, __HIP_MEMORY_SCOPE_AGENT) < 16u * T_LEN) {}
    __builtin_amdgcn_fence(__ATOMIC_ACQUIRE, "agent");

    __shared__ float hsm[16 * 256];
    for (int i = tid; i < 16 * 256; i += 256) hsm[i] = hfin[(size_t)bg * 16 * 256 + i];
    __syncthreads();
    for (int idx = tid; idx < 16 * 32; idx += 256) {
        int m = idx >> 5;
        int d = cb * 32 + (idx & 31);
        float s = fcb[d];
        for (int j = 0; j < NH; ++j) s += hsm[m * 256 + j] * fcw[j * DOUT + d];
        out[(bg * 16 + m) * DOUT + d] = s;
    }
}

extern "C" void kernel_launch(void* const* d_in, const int* in_sizes, int n_in,
                              void* d_out, int out_size, void* d_ws, size_t ws_size,
                              hipStream_t stream) {
    (void)in_sizes; (void)n_in; (void)ws_size; (void)out_size;
    const float* x   = (const float*)d_in[0];
    const float* Wx  = (const float*)d_in[1];
    const float* Wh  = (const float*)d_in[2];
    const float* b   = (const float*)d_in[3];
    const float* fcw = (const float*)d_in[4];
    const float* fcb = (const float*)d_in[5];
    float* out = (float*)d_out;

    // zero the sync counters + h ping-pong buffers (h0 = 0)
    hipMemsetAsync(d_ws, 0, 66560, stream);
    hipLaunchKernelGGL(lstm_scan, dim3(32), dim3(256), 0, stream,
                       x, Wx, Wh, b, fcw, fcb, out, d_ws);
}